// Round 5
// baseline (466.642 us; speedup 1.0000x reference)
//
#include <hip/hip_runtime.h>

// ---------------------------------------------------------------------------
// GRACE GCN 2-layer forward, CSR-gather formulation, bf16 intermediates.
//   h1' = (X W1) * dinv      (bf16, pre-scaled by source dinv)
//   h2  = prelu(dinv_d*(h1'_d + sum_j h1'_es[j]) + b1)    (bf16)
//   g'  = (h2 W2) * dinv     (bf16)
//   out = prelu(dinv_d*(g'_d + sum_j g'_es[j]) + b2)      (f32)
// CSR build via 64-node bucketed counting sort (R4's flat scatter had 16x
// write amplification: 105 MB HBM writes for a 6.4 MB es buffer). Bucket-major
// es layout with per-bucket capacity padding removes the global scan: each
// bucket block computes its own offsets from an LDS histogram+scan.
// ---------------------------------------------------------------------------

#define THREADS 256
#define BSH 6                    // 64 nodes per bucket
#define BN  (1 << BSH)

typedef unsigned short bf16_t;

__device__ __forceinline__ float bflo(unsigned int w) {
    union { unsigned int u; float f; } v; v.u = w << 16; return v.f;
}
__device__ __forceinline__ float bfhi(unsigned int w) {
    union { unsigned int u; float f; } v; v.u = w & 0xffff0000u; return v.f;
}
__device__ __forceinline__ unsigned int f2bf(float f) {  // RNE
    union { float f; unsigned int u; } v; v.f = f;
    return (v.u + 0x7fffu + ((v.u >> 16) & 1u)) >> 16;
}

// -------------------- bucketed counting sort --------------------
__global__ void zero_ccnt_kernel(int* __restrict__ ccnt, int nbkt) {
    int i = blockIdx.x * blockDim.x + threadIdx.x;
    if (i < nbkt) ccnt[i] = 0;
}

// staging[b*cap + pos] = src | ((dst&63) << 25)   (requires n < 2^25)
__global__ void bucket_scatter_kernel(const int* __restrict__ src,
                                      const int* __restrict__ dst,
                                      int* __restrict__ ccnt,
                                      unsigned int* __restrict__ staging,
                                      int e, int cap) {
    int i = blockIdx.x * blockDim.x + threadIdx.x;
    if (i >= e) return;
    unsigned int s = (unsigned int)src[i];
    int d = dst[i];
    int b = d >> BSH;
    int pos = atomicAdd(&ccnt[b], 1);
    staging[(size_t)b * cap + pos] = s | ((unsigned int)(d & (BN - 1)) << 25);
}

// One block per bucket: LDS histogram -> LDS scan -> off/cnt/dinv -> local es scatter.
__global__ __launch_bounds__(THREADS) void bucket_build_kernel(
    const unsigned int* __restrict__ staging, const int* __restrict__ ccnt,
    int cap, float* __restrict__ dinv, int* __restrict__ off, int* __restrict__ cnt,
    int* __restrict__ es, int n) {
    __shared__ int scnt[BN];
    __shared__ int soff[BN];
    int b = blockIdx.x;
    int t = threadIdx.x;
    if (t < BN) scnt[t] = 0;
    __syncthreads();

    int m = ccnt[b];
    const unsigned int* sb = staging + (size_t)b * cap;
    for (int i = t; i < m; i += THREADS) atomicAdd(&scnt[sb[i] >> 25], 1);
    __syncthreads();

    // inclusive Hillis-Steele scan over BN counters
    if (t < BN) soff[t] = scnt[t];
    __syncthreads();
    for (int d = 1; d < BN; d <<= 1) {
        int v = (t < BN && t >= d) ? soff[t - d] : 0;
        __syncthreads();
        if (t < BN) soff[t] += v;
        __syncthreads();
    }

    int ebase = b * cap;
    if (t < BN) {
        int ex = soff[t] - scnt[t];     // exclusive
        int node = (b << BSH) + t;
        if (node < n) {
            off[node]  = ebase + ex;
            cnt[node]  = scnt[t];
            dinv[node] = rsqrtf((float)(scnt[t] + 1));  // +1 self loop
        }
        soff[t] = ex;                   // becomes local cursor
    }
    __syncthreads();

    for (int i = t; i < m; i += THREADS) {
        unsigned int pk = sb[i];
        int pos = atomicAdd(&soff[pk >> 25], 1);
        es[ebase + pos] = (int)(pk & 0x01FFFFFFu);
    }
}

// -------------------- dense GEMM: H = (X[n,128] @ W[128,OUTC]) * rowscale ----
// Register-blocked 8 rows x 4 cols/thread; W staged in LDS (f32); output bf16.
template <int OUTC, bool XBF>
__global__ __launch_bounds__(THREADS) void gemm_kernel(const void* __restrict__ Xv,
                                                       const float* __restrict__ W,
                                                       const float* __restrict__ rowscale,
                                                       bf16_t* __restrict__ H, int n) {
    constexpr int CG = OUTC / 4;
    constexpr int RG = THREADS / CG;
    constexpr int R  = 8;
    constexpr int ROWS = RG * R;
    __shared__ float Wl[128 * OUTC];
    {
        const float4* Wv = reinterpret_cast<const float4*>(W);
        float4* Wlv = reinterpret_cast<float4*>(Wl);
        for (int i = threadIdx.x; i < 128 * OUTC / 4; i += THREADS) Wlv[i] = Wv[i];
    }
    __syncthreads();

    int cg = (int)threadIdx.x % CG;
    int rg = (int)threadIdx.x / CG;
    int rbase = blockIdx.x * ROWS + rg * R;

    int rr[R];
#pragma unroll
    for (int r = 0; r < R; ++r) {
        int q = rbase + r;
        rr[r] = q < n ? q : (n - 1);   // clamp: loads in-bounds, store guarded
    }

    float4 acc[R];
#pragma unroll
    for (int r = 0; r < R; ++r) acc[r] = make_float4(0.f, 0.f, 0.f, 0.f);

#pragma unroll 4
    for (int k0 = 0; k0 < 128; k0 += 4) {
        float4 w0 = *reinterpret_cast<const float4*>(&Wl[(k0 + 0) * OUTC + cg * 4]);
        float4 w1 = *reinterpret_cast<const float4*>(&Wl[(k0 + 1) * OUTC + cg * 4]);
        float4 w2 = *reinterpret_cast<const float4*>(&Wl[(k0 + 2) * OUTC + cg * 4]);
        float4 w3 = *reinterpret_cast<const float4*>(&Wl[(k0 + 3) * OUTC + cg * 4]);
#pragma unroll
        for (int r = 0; r < R; ++r) {
            float xs0, xs1, xs2, xs3;
            if constexpr (XBF) {
                const bf16_t* Xb = (const bf16_t*)Xv;
                uint2 xu = *reinterpret_cast<const uint2*>(Xb + (size_t)rr[r] * 128 + k0);
                xs0 = bflo(xu.x); xs1 = bfhi(xu.x); xs2 = bflo(xu.y); xs3 = bfhi(xu.y);
            } else {
                float4 xv = *reinterpret_cast<const float4*>((const float*)Xv + (size_t)rr[r] * 128 + k0);
                xs0 = xv.x; xs1 = xv.y; xs2 = xv.z; xs3 = xv.w;
            }
            acc[r].x += xs0 * w0.x + xs1 * w1.x + xs2 * w2.x + xs3 * w3.x;
            acc[r].y += xs0 * w0.y + xs1 * w1.y + xs2 * w2.y + xs3 * w3.y;
            acc[r].z += xs0 * w0.z + xs1 * w1.z + xs2 * w2.z + xs3 * w3.z;
            acc[r].w += xs0 * w0.w + xs1 * w1.w + xs2 * w2.w + xs3 * w3.w;
        }
    }

#pragma unroll
    for (int r = 0; r < R; ++r) {
        int q = rbase + r;
        if (q < n) {
            float s = rowscale[q];
            ushort4 o;
            o.x = (unsigned short)f2bf(acc[r].x * s);
            o.y = (unsigned short)f2bf(acc[r].y * s);
            o.z = (unsigned short)f2bf(acc[r].z * s);
            o.w = (unsigned short)f2bf(acc[r].w * s);
            *reinterpret_cast<ushort4*>(&H[(size_t)q * OUTC + cg * 4]) = o;
        }
    }
}

// -------------------- CSR aggregate + bias + PReLU (fused, bf16 gather) -----
// out[i,:] = prelu( dinv[i]*(H'[i,:] + sum_j H'[es[j],:]) + b, a )
template <int F, bool OUTBF>
__global__ __launch_bounds__(THREADS) void agg_kernel(const bf16_t* __restrict__ H,
                                                      const float* __restrict__ dinv,
                                                      const int* __restrict__ off,
                                                      const int* __restrict__ cnt,
                                                      const int* __restrict__ es,
                                                      const float* __restrict__ bias,
                                                      const float* __restrict__ a_ptr,
                                                      void* __restrict__ outv, int n) {
    constexpr int TPN = F / 8;                 // threads per node (8 bf16 = 16B each)
    int node = blockIdx.x * (THREADS / TPN) + (int)threadIdx.x / TPN;
    int l8   = (int)threadIdx.x % TPN;
    if (node >= n) return;
    const int fbase = l8 * 8;

    float acc[8];
    {   // self term (H already pre-scaled by dinv[node])
        uint4 v = *reinterpret_cast<const uint4*>(H + (size_t)node * F + fbase);
        acc[0] = bflo(v.x); acc[1] = bfhi(v.x);
        acc[2] = bflo(v.y); acc[3] = bfhi(v.y);
        acc[4] = bflo(v.z); acc[5] = bfhi(v.z);
        acc[6] = bflo(v.w); acc[7] = bfhi(v.w);
    }

    int j0 = off[node];
    int m  = cnt[node];
    int i = 0;
    for (; i + 3 < m; i += 4) {
        int s0 = es[j0 + i], s1 = es[j0 + i + 1], s2 = es[j0 + i + 2], s3 = es[j0 + i + 3];
        uint4 v0 = *reinterpret_cast<const uint4*>(H + (size_t)s0 * F + fbase);
        uint4 v1 = *reinterpret_cast<const uint4*>(H + (size_t)s1 * F + fbase);
        uint4 v2 = *reinterpret_cast<const uint4*>(H + (size_t)s2 * F + fbase);
        uint4 v3 = *reinterpret_cast<const uint4*>(H + (size_t)s3 * F + fbase);
        acc[0] += (bflo(v0.x) + bflo(v1.x)) + (bflo(v2.x) + bflo(v3.x));
        acc[1] += (bfhi(v0.x) + bfhi(v1.x)) + (bfhi(v2.x) + bfhi(v3.x));
        acc[2] += (bflo(v0.y) + bflo(v1.y)) + (bflo(v2.y) + bflo(v3.y));
        acc[3] += (bfhi(v0.y) + bfhi(v1.y)) + (bfhi(v2.y) + bfhi(v3.y));
        acc[4] += (bflo(v0.z) + bflo(v1.z)) + (bflo(v2.z) + bflo(v3.z));
        acc[5] += (bfhi(v0.z) + bfhi(v1.z)) + (bfhi(v2.z) + bfhi(v3.z));
        acc[6] += (bflo(v0.w) + bflo(v1.w)) + (bflo(v2.w) + bflo(v3.w));
        acc[7] += (bfhi(v0.w) + bfhi(v1.w)) + (bfhi(v2.w) + bfhi(v3.w));
    }
    for (; i < m; ++i) {
        int s0 = es[j0 + i];
        uint4 v0 = *reinterpret_cast<const uint4*>(H + (size_t)s0 * F + fbase);
        acc[0] += bflo(v0.x); acc[1] += bfhi(v0.x);
        acc[2] += bflo(v0.y); acc[3] += bfhi(v0.y);
        acc[4] += bflo(v0.z); acc[5] += bfhi(v0.z);
        acc[6] += bflo(v0.w); acc[7] += bfhi(v0.w);
    }

    float di = dinv[node];
    float a  = *a_ptr;
    float4 b0 = *reinterpret_cast<const float4*>(bias + fbase);
    float4 b1 = *reinterpret_cast<const float4*>(bias + fbase + 4);
    float bb[8] = {b0.x, b0.y, b0.z, b0.w, b1.x, b1.y, b1.z, b1.w};
    float o[8];
#pragma unroll
    for (int k = 0; k < 8; ++k) {
        float v = acc[k] * di + bb[k];
        o[k] = v >= 0.f ? v : a * v;
    }

    if constexpr (OUTBF) {
        uint4 w;
        w.x = f2bf(o[0]) | (f2bf(o[1]) << 16);
        w.y = f2bf(o[2]) | (f2bf(o[3]) << 16);
        w.z = f2bf(o[4]) | (f2bf(o[5]) << 16);
        w.w = f2bf(o[6]) | (f2bf(o[7]) << 16);
        *reinterpret_cast<uint4*>((bf16_t*)outv + (size_t)node * F + fbase) = w;
    } else {
        float* op = (float*)outv + (size_t)node * F + fbase;
        *reinterpret_cast<float4*>(op)     = make_float4(o[0], o[1], o[2], o[3]);
        *reinterpret_cast<float4*>(op + 4) = make_float4(o[4], o[5], o[6], o[7]);
    }
}

extern "C" void kernel_launch(void* const* d_in, const int* in_sizes, int n_in,
                              void* d_out, int out_size, void* d_ws, size_t ws_size,
                              hipStream_t stream) {
    const float* x   = (const float*)d_in[0];
    const int*   ei  = (const int*)d_in[1];
    const float* W1  = (const float*)d_in[2];
    const float* b1  = (const float*)d_in[3];
    const float* W2  = (const float*)d_in[4];
    const float* b2  = (const float*)d_in[5];
    const float* a   = (const float*)d_in[6];

    const int IN  = 128;
    const int HID = 128;
    const int OUT = 64;
    const int n = in_sizes[0] / IN;       // 100000
    const int e = in_sizes[1] / 2;        // 1600000
    const int* src = ei;
    const int* dst = ei + e;

    const int nbkt = (n + BN - 1) >> BSH;              // 1563
    const int cap  = ((e + nbkt - 1) / nbkt) * 2 + 256; // ~2304, >> 40 sigma headroom

    auto align = [](size_t v) { return (v + 255) / 256 * 256; };
    char* ws = (char*)d_ws;
    size_t o = 0;
    int*          ccnt    = (int*)(ws + o);          o += align((size_t)nbkt * 4);
    float*        dinv    = (float*)(ws + o);        o += align((size_t)n * 4);
    int*          off     = (int*)(ws + o);          o += align((size_t)n * 4);
    int*          cnt     = (int*)(ws + o);          o += align((size_t)n * 4);
    unsigned int* staging = (unsigned int*)(ws + o); o += align((size_t)nbkt * cap * 4);
    int*          es      = (int*)(ws + o);          o += align((size_t)nbkt * cap * 4);
    bf16_t*       h1      = (bf16_t*)(ws + o);       o += align((size_t)n * HID * 2);
    bf16_t*       h2      = (bf16_t*)(ws + o);       o += align((size_t)n * HID * 2);
    bf16_t*       g       = (bf16_t*)(ws + o);       o += align((size_t)n * OUT * 2);

    float* out = (float*)d_out;

    // ---- CSR build (bucketed counting sort) ----
    zero_ccnt_kernel<<<(nbkt + THREADS - 1) / THREADS, THREADS, 0, stream>>>(ccnt, nbkt);
    bucket_scatter_kernel<<<(e + THREADS - 1) / THREADS, THREADS, 0, stream>>>(
        src, dst, ccnt, staging, e, cap);
    bucket_build_kernel<<<nbkt, THREADS, 0, stream>>>(staging, ccnt, cap, dinv, off, cnt, es, n);

    // ---- layer 1 ----
    {
        constexpr int ROWS = (THREADS / (128 / 4)) * 8;  // 64 rows/block
        int gb = (n + ROWS - 1) / ROWS;
        gemm_kernel<128, false><<<gb, THREADS, 0, stream>>>(x, W1, dinv, h1, n);
    }
    {
        constexpr int NPB = THREADS / (128 / 8);   // 16 nodes/block
        int gb = (n + NPB - 1) / NPB;
        agg_kernel<128, true><<<gb, THREADS, 0, stream>>>(h1, dinv, off, cnt, es, b1, a, h2, n);
    }

    // ---- layer 2 ----
    {
        constexpr int ROWS = (THREADS / (64 / 4)) * 8;   // 128 rows/block
        int gb = (n + ROWS - 1) / ROWS;
        gemm_kernel<64, true><<<gb, THREADS, 0, stream>>>(h2, W2, dinv, g, n);
    }
    {
        constexpr int NPB = THREADS / (64 / 8);    // 32 nodes/block
        int gb = (n + NPB - 1) / NPB;
        agg_kernel<64, false><<<gb, THREADS, 0, stream>>>(g, dinv, off, cnt, es, b2, a, out, n);
    }

    (void)ws_size; (void)n_in; (void)out_size;
}

// Round 6
// 277.247 us; speedup vs baseline: 1.6831x; 1.6831x over previous
//
#include <hip/hip_runtime.h>

// ---------------------------------------------------------------------------
// GRACE GCN 2-layer forward, CSR-gather formulation, bf16 intermediates.
//   h1' = (X W1) * dinv      (bf16, pre-scaled by source dinv)
//   h2  = prelu(dinv_d*(h1'_d + sum_j h1'_es[j]) + b1)    (bf16)
//   g'  = (h2 W2) * dinv     (bf16)
//   out = prelu(dinv_d*(g'_d + sum_j g'_es[j]) + b2)      (f32)
// CSR build via radix-partition (no global atomics): per-block LDS histogram
// over 128-node bins -> global exclusive scan of hist[bin][blk] -> rank+scatter
// with LDS counters into disjoint (bin,blk) segments (one ~64B line each,
// written once -> no write amplification) -> per-bin LDS counting sort giving
// exact dense CSR. R5's coarse-cursor scatter was atomic-contention-bound
// (1024 atomics/counter, 240us); R4's flat scatter had 16x write amp (105MB).
// ---------------------------------------------------------------------------

#define THREADS 256
#define SCAN_CHUNK 1024   // 256 threads x 4 elements
#define NBLK  128         // partition blocks (fixed chunking)
#define BINSH 7           // 128 nodes per bin
#define BINSZ 128
#define KMAX  1024        // max bins (supports n <= 131072)

typedef unsigned short bf16_t;

__device__ __forceinline__ float bflo(unsigned int w) {
    union { unsigned int u; float f; } v; v.u = w << 16; return v.f;
}
__device__ __forceinline__ float bfhi(unsigned int w) {
    union { unsigned int u; float f; } v; v.u = w & 0xffff0000u; return v.f;
}
__device__ __forceinline__ unsigned int f2bf(float f) {  // RNE
    union { float f; unsigned int u; } v; v.f = f;
    return (v.u + 0x7fffu + ((v.u >> 16) & 1u)) >> 16;
}

// -------------------- pass 1: per-block bin histogram --------------------
__global__ __launch_bounds__(THREADS) void hist_kernel(const int* __restrict__ dst,
                                                       int* __restrict__ hist,
                                                       int e, int K, int chunk) {
    __shared__ int h[KMAX];
    int t = threadIdx.x, b = blockIdx.x;
    for (int i = t; i < K; i += THREADS) h[i] = 0;
    __syncthreads();
    int lo = b * chunk, hi = min(lo + chunk, e);
    for (int i = lo + t; i < hi; i += THREADS) atomicAdd(&h[dst[i] >> BINSH], 1);
    __syncthreads();
    for (int i = t; i < K; i += THREADS) hist[i * NBLK + b] = h[i];  // bin-major
}

// -------------------- exclusive scan over m elements (3 phases) ------------
__global__ void scan_phaseA_kernel(const int* __restrict__ in, int* __restrict__ bsum, int m) {
    __shared__ int sdata[256];
    int base = blockIdx.x * SCAN_CHUNK;
    int t = threadIdx.x;
    int s = 0;
#pragma unroll
    for (int k = 0; k < 4; ++k) {
        int idx = base + t * 4 + k;
        if (idx < m) s += in[idx];
    }
    sdata[t] = s;
    __syncthreads();
    for (int d = 128; d > 0; d >>= 1) {
        if (t < d) sdata[t] += sdata[t + d];
        __syncthreads();
    }
    if (t == 0) bsum[blockIdx.x] = sdata[0];
}

__global__ void scan_phaseB_kernel(int* __restrict__ bsum, int nb) {
    __shared__ int sdata[256];
    __shared__ int carry;
    int t = threadIdx.x;
    if (t == 0) carry = 0;
    __syncthreads();
    for (int base = 0; base < nb; base += 256) {
        int idx = base + t;
        int v = (idx < nb) ? bsum[idx] : 0;
        sdata[t] = v;
        __syncthreads();
        for (int d = 1; d < 256; d <<= 1) {
            int u = (t >= d) ? sdata[t - d] : 0;
            __syncthreads();
            sdata[t] += u;
            __syncthreads();
        }
        int excl = sdata[t] - v + carry;
        if (idx < nb) bsum[idx] = excl;
        int tot = sdata[255];
        __syncthreads();
        if (t == 0) carry += tot;
        __syncthreads();
    }
}

__global__ void scan_phaseC_kernel(const int* __restrict__ in, const int* __restrict__ bsum,
                                   int* __restrict__ outx, int m) {
    __shared__ int sdata[256];
    int base = blockIdx.x * SCAN_CHUNK;
    int t = threadIdx.x;
    int v[4];
    int s = 0;
#pragma unroll
    for (int k = 0; k < 4; ++k) {
        int idx = base + t * 4 + k;
        v[k] = (idx < m) ? in[idx] : 0;
        s += v[k];
    }
    sdata[t] = s;
    __syncthreads();
    for (int d = 1; d < 256; d <<= 1) {
        int u = (t >= d) ? sdata[t - d] : 0;
        __syncthreads();
        sdata[t] += u;
        __syncthreads();
    }
    int run = bsum[blockIdx.x] + sdata[t] - s;  // exclusive base
#pragma unroll
    for (int k = 0; k < 4; ++k) {
        int idx = base + t * 4 + k;
        if (idx < m) { outx[idx] = run; run += v[k]; }
    }
}

// -------------------- pass 2: rank via LDS + scatter to (bin,blk) segment ---
__global__ __launch_bounds__(THREADS) void rank_scatter_kernel(const int* __restrict__ src,
                                                               const int* __restrict__ dst,
                                                               const int* __restrict__ hoff,
                                                               unsigned int* __restrict__ sorted,
                                                               int e, int K, int chunk) {
    __shared__ int cntl[KMAX];
    __shared__ int basel[KMAX];
    int t = threadIdx.x, b = blockIdx.x;
    for (int i = t; i < K; i += THREADS) { cntl[i] = 0; basel[i] = hoff[i * NBLK + b]; }
    __syncthreads();
    int lo = b * chunk, hi = min(lo + chunk, e);
    for (int i = lo + t; i < hi; i += THREADS) {
        int d = dst[i];
        int bin = d >> BINSH;
        int r = atomicAdd(&cntl[bin], 1);
        sorted[basel[bin] + r] = (unsigned int)src[i] | ((unsigned int)(d & (BINSZ - 1)) << 25);
    }
}

// -------------------- pass 3: per-bin counting sort -> exact CSR ------------
__global__ __launch_bounds__(THREADS) void bin_build_kernel(const unsigned int* __restrict__ sorted,
                                                            const int* __restrict__ hoff,
                                                            float* __restrict__ dinv,
                                                            int* __restrict__ off,
                                                            int* __restrict__ cnt,
                                                            int* __restrict__ es,
                                                            int n, int e, int K) {
    __shared__ int scnt[BINSZ];
    __shared__ int soff[BINSZ];
    int b = blockIdx.x, t = threadIdx.x;
    int base = hoff[b * NBLK];
    int end  = (b + 1 < K) ? hoff[(b + 1) * NBLK] : e;
    int m = end - base;
    if (t < BINSZ) scnt[t] = 0;
    __syncthreads();
    for (int i = t; i < m; i += THREADS) atomicAdd(&scnt[sorted[base + i] >> 25], 1);
    __syncthreads();
    if (t < BINSZ) soff[t] = scnt[t];
    __syncthreads();
    for (int d = 1; d < BINSZ; d <<= 1) {
        int v = (t < BINSZ && t >= d) ? soff[t - d] : 0;
        __syncthreads();
        if (t < BINSZ) soff[t] += v;
        __syncthreads();
    }
    if (t < BINSZ) {
        int ex = soff[t] - scnt[t];     // exclusive
        int node = (b << BINSH) + t;
        if (node < n) {
            off[node]  = base + ex;
            cnt[node]  = scnt[t];
            dinv[node] = rsqrtf((float)(scnt[t] + 1));  // +1 self loop
        }
        soff[t] = ex;                   // local cursor
    }
    __syncthreads();
    for (int i = t; i < m; i += THREADS) {
        unsigned int pk = sorted[base + i];
        int pos = atomicAdd(&soff[pk >> 25], 1);
        es[base + pos] = (int)(pk & 0x01FFFFFFu);
    }
}

// -------------------- dense GEMM: H = (X[n,128] @ W[128,OUTC]) * rowscale ----
template <int OUTC, bool XBF>
__global__ __launch_bounds__(THREADS) void gemm_kernel(const void* __restrict__ Xv,
                                                       const float* __restrict__ W,
                                                       const float* __restrict__ rowscale,
                                                       bf16_t* __restrict__ H, int n) {
    constexpr int CG = OUTC / 4;
    constexpr int RG = THREADS / CG;
    constexpr int R  = 8;
    constexpr int ROWS = RG * R;
    __shared__ float Wl[128 * OUTC];
    {
        const float4* Wv = reinterpret_cast<const float4*>(W);
        float4* Wlv = reinterpret_cast<float4*>(Wl);
        for (int i = threadIdx.x; i < 128 * OUTC / 4; i += THREADS) Wlv[i] = Wv[i];
    }
    __syncthreads();

    int cg = (int)threadIdx.x % CG;
    int rg = (int)threadIdx.x / CG;
    int rbase = blockIdx.x * ROWS + rg * R;

    int rr[R];
#pragma unroll
    for (int r = 0; r < R; ++r) {
        int q = rbase + r;
        rr[r] = q < n ? q : (n - 1);   // clamp: loads in-bounds, store guarded
    }

    float4 acc[R];
#pragma unroll
    for (int r = 0; r < R; ++r) acc[r] = make_float4(0.f, 0.f, 0.f, 0.f);

#pragma unroll 4
    for (int k0 = 0; k0 < 128; k0 += 4) {
        float4 w0 = *reinterpret_cast<const float4*>(&Wl[(k0 + 0) * OUTC + cg * 4]);
        float4 w1 = *reinterpret_cast<const float4*>(&Wl[(k0 + 1) * OUTC + cg * 4]);
        float4 w2 = *reinterpret_cast<const float4*>(&Wl[(k0 + 2) * OUTC + cg * 4]);
        float4 w3 = *reinterpret_cast<const float4*>(&Wl[(k0 + 3) * OUTC + cg * 4]);
#pragma unroll
        for (int r = 0; r < R; ++r) {
            float xs0, xs1, xs2, xs3;
            if constexpr (XBF) {
                const bf16_t* Xb = (const bf16_t*)Xv;
                uint2 xu = *reinterpret_cast<const uint2*>(Xb + (size_t)rr[r] * 128 + k0);
                xs0 = bflo(xu.x); xs1 = bfhi(xu.x); xs2 = bflo(xu.y); xs3 = bfhi(xu.y);
            } else {
                float4 xv = *reinterpret_cast<const float4*>((const float*)Xv + (size_t)rr[r] * 128 + k0);
                xs0 = xv.x; xs1 = xv.y; xs2 = xv.z; xs3 = xv.w;
            }
            acc[r].x += xs0 * w0.x + xs1 * w1.x + xs2 * w2.x + xs3 * w3.x;
            acc[r].y += xs0 * w0.y + xs1 * w1.y + xs2 * w2.y + xs3 * w3.y;
            acc[r].z += xs0 * w0.z + xs1 * w1.z + xs2 * w2.z + xs3 * w3.z;
            acc[r].w += xs0 * w0.w + xs1 * w1.w + xs2 * w2.w + xs3 * w3.w;
        }
    }

#pragma unroll
    for (int r = 0; r < R; ++r) {
        int q = rbase + r;
        if (q < n) {
            float s = rowscale[q];
            ushort4 o;
            o.x = (unsigned short)f2bf(acc[r].x * s);
            o.y = (unsigned short)f2bf(acc[r].y * s);
            o.z = (unsigned short)f2bf(acc[r].z * s);
            o.w = (unsigned short)f2bf(acc[r].w * s);
            *reinterpret_cast<ushort4*>(&H[(size_t)q * OUTC + cg * 4]) = o;
        }
    }
}

// -------------------- CSR aggregate + bias + PReLU (fused, bf16 gather) -----
// out[i,:] = prelu( dinv[i]*(H'[i,:] + sum_j H'[es[j],:]) + b, a )
template <int F, bool OUTBF>
__global__ __launch_bounds__(THREADS) void agg_kernel(const bf16_t* __restrict__ H,
                                                      const float* __restrict__ dinv,
                                                      const int* __restrict__ off,
                                                      const int* __restrict__ cnt,
                                                      const int* __restrict__ es,
                                                      const float* __restrict__ bias,
                                                      const float* __restrict__ a_ptr,
                                                      void* __restrict__ outv, int n) {
    constexpr int TPN = F / 8;                 // threads per node (8 bf16 = 16B each)
    int node = blockIdx.x * (THREADS / TPN) + (int)threadIdx.x / TPN;
    int l8   = (int)threadIdx.x % TPN;
    if (node >= n) return;
    const int fbase = l8 * 8;

    float acc[8];
    {   // self term (H already pre-scaled by dinv[node])
        uint4 v = *reinterpret_cast<const uint4*>(H + (size_t)node * F + fbase);
        acc[0] = bflo(v.x); acc[1] = bfhi(v.x);
        acc[2] = bflo(v.y); acc[3] = bfhi(v.y);
        acc[4] = bflo(v.z); acc[5] = bfhi(v.z);
        acc[6] = bflo(v.w); acc[7] = bfhi(v.w);
    }

    int j0 = off[node];
    int m  = cnt[node];
    int i = 0;
    for (; i + 3 < m; i += 4) {
        int s0 = es[j0 + i], s1 = es[j0 + i + 1], s2 = es[j0 + i + 2], s3 = es[j0 + i + 3];
        uint4 v0 = *reinterpret_cast<const uint4*>(H + (size_t)s0 * F + fbase);
        uint4 v1 = *reinterpret_cast<const uint4*>(H + (size_t)s1 * F + fbase);
        uint4 v2 = *reinterpret_cast<const uint4*>(H + (size_t)s2 * F + fbase);
        uint4 v3 = *reinterpret_cast<const uint4*>(H + (size_t)s3 * F + fbase);
        acc[0] += (bflo(v0.x) + bflo(v1.x)) + (bflo(v2.x) + bflo(v3.x));
        acc[1] += (bfhi(v0.x) + bfhi(v1.x)) + (bfhi(v2.x) + bfhi(v3.x));
        acc[2] += (bflo(v0.y) + bflo(v1.y)) + (bflo(v2.y) + bflo(v3.y));
        acc[3] += (bfhi(v0.y) + bfhi(v1.y)) + (bfhi(v2.y) + bfhi(v3.y));
        acc[4] += (bflo(v0.z) + bflo(v1.z)) + (bflo(v2.z) + bflo(v3.z));
        acc[5] += (bfhi(v0.z) + bfhi(v1.z)) + (bfhi(v2.z) + bfhi(v3.z));
        acc[6] += (bflo(v0.w) + bflo(v1.w)) + (bflo(v2.w) + bflo(v3.w));
        acc[7] += (bfhi(v0.w) + bfhi(v1.w)) + (bfhi(v2.w) + bfhi(v3.w));
    }
    for (; i < m; ++i) {
        int s0 = es[j0 + i];
        uint4 v0 = *reinterpret_cast<const uint4*>(H + (size_t)s0 * F + fbase);
        acc[0] += bflo(v0.x); acc[1] += bfhi(v0.x);
        acc[2] += bflo(v0.y); acc[3] += bfhi(v0.y);
        acc[4] += bflo(v0.z); acc[5] += bfhi(v0.z);
        acc[6] += bflo(v0.w); acc[7] += bfhi(v0.w);
    }

    float di = dinv[node];
    float a  = *a_ptr;
    float4 b0 = *reinterpret_cast<const float4*>(bias + fbase);
    float4 b1 = *reinterpret_cast<const float4*>(bias + fbase + 4);
    float bb[8] = {b0.x, b0.y, b0.z, b0.w, b1.x, b1.y, b1.z, b1.w};
    float o[8];
#pragma unroll
    for (int k = 0; k < 8; ++k) {
        float v = acc[k] * di + bb[k];
        o[k] = v >= 0.f ? v : a * v;
    }

    if constexpr (OUTBF) {
        uint4 w;
        w.x = f2bf(o[0]) | (f2bf(o[1]) << 16);
        w.y = f2bf(o[2]) | (f2bf(o[3]) << 16);
        w.z = f2bf(o[4]) | (f2bf(o[5]) << 16);
        w.w = f2bf(o[6]) | (f2bf(o[7]) << 16);
        *reinterpret_cast<uint4*>((bf16_t*)outv + (size_t)node * F + fbase) = w;
    } else {
        float* op = (float*)outv + (size_t)node * F + fbase;
        *reinterpret_cast<float4*>(op)     = make_float4(o[0], o[1], o[2], o[3]);
        *reinterpret_cast<float4*>(op + 4) = make_float4(o[4], o[5], o[6], o[7]);
    }
}

extern "C" void kernel_launch(void* const* d_in, const int* in_sizes, int n_in,
                              void* d_out, int out_size, void* d_ws, size_t ws_size,
                              hipStream_t stream) {
    const float* x   = (const float*)d_in[0];
    const int*   ei  = (const int*)d_in[1];
    const float* W1  = (const float*)d_in[2];
    const float* b1  = (const float*)d_in[3];
    const float* W2  = (const float*)d_in[4];
    const float* b2  = (const float*)d_in[5];
    const float* a   = (const float*)d_in[6];

    const int IN  = 128;
    const int HID = 128;
    const int OUT = 64;
    const int n = in_sizes[0] / IN;       // 100000
    const int e = in_sizes[1] / 2;        // 1600000
    const int* src = ei;
    const int* dst = ei + e;

    const int K     = (n + BINSZ - 1) >> BINSH;   // 782 bins
    const int chunk = (e + NBLK - 1) / NBLK;      // 12500 edges/block
    const int M     = K * NBLK;                   // 100096 hist entries
    const int nb    = (M + SCAN_CHUNK - 1) / SCAN_CHUNK;

    auto align = [](size_t v) { return (v + 255) / 256 * 256; };
    char* ws = (char*)d_ws;
    size_t o = 0;
    int*          hist   = (int*)(ws + o);          o += align((size_t)M * 4);
    int*          hoff   = (int*)(ws + o);          o += align((size_t)M * 4);
    int*          bsum   = (int*)(ws + o);          o += align((size_t)nb * 4);
    unsigned int* sorted = (unsigned int*)(ws + o); o += align((size_t)e * 4);
    int*          es     = (int*)(ws + o);          o += align((size_t)e * 4);
    float*        dinv   = (float*)(ws + o);        o += align((size_t)n * 4);
    int*          off    = (int*)(ws + o);          o += align((size_t)n * 4);
    int*          cnt    = (int*)(ws + o);          o += align((size_t)n * 4);
    bf16_t*       h1     = (bf16_t*)(ws + o);       o += align((size_t)n * HID * 2);
    bf16_t*       h2     = (bf16_t*)(ws + o);       o += align((size_t)n * HID * 2);
    bf16_t*       g      = (bf16_t*)(ws + o);       o += align((size_t)n * OUT * 2);

    float* out = (float*)d_out;

    // ---- CSR build: radix partition + per-bin counting sort ----
    hist_kernel<<<NBLK, THREADS, 0, stream>>>(dst, hist, e, K, chunk);
    scan_phaseA_kernel<<<nb, THREADS, 0, stream>>>(hist, bsum, M);
    scan_phaseB_kernel<<<1, THREADS, 0, stream>>>(bsum, nb);
    scan_phaseC_kernel<<<nb, THREADS, 0, stream>>>(hist, bsum, hoff, M);
    rank_scatter_kernel<<<NBLK, THREADS, 0, stream>>>(src, dst, hoff, sorted, e, K, chunk);
    bin_build_kernel<<<K, THREADS, 0, stream>>>(sorted, hoff, dinv, off, cnt, es, n, e, K);

    // ---- layer 1 ----
    {
        constexpr int ROWS = (THREADS / (128 / 4)) * 8;  // 64 rows/block
        int gb = (n + ROWS - 1) / ROWS;
        gemm_kernel<128, false><<<gb, THREADS, 0, stream>>>(x, W1, dinv, h1, n);
    }
    {
        constexpr int NPB = THREADS / (128 / 8);   // 16 nodes/block
        int gb = (n + NPB - 1) / NPB;
        agg_kernel<128, true><<<gb, THREADS, 0, stream>>>(h1, dinv, off, cnt, es, b1, a, h2, n);
    }

    // ---- layer 2 ----
    {
        constexpr int ROWS = (THREADS / (64 / 4)) * 8;   // 128 rows/block
        int gb = (n + ROWS - 1) / ROWS;
        gemm_kernel<64, true><<<gb, THREADS, 0, stream>>>(h2, W2, dinv, g, n);
    }
    {
        constexpr int NPB = THREADS / (64 / 8);    // 32 nodes/block
        int gb = (n + NPB - 1) / NPB;
        agg_kernel<64, false><<<gb, THREADS, 0, stream>>>(g, dinv, off, cnt, es, b2, a, out, n);
    }

    (void)ws_size; (void)n_in; (void)out_size;
}

// Round 7
// 227.547 us; speedup vs baseline: 2.0507x; 1.2184x over previous
//
#include <hip/hip_runtime.h>

// ---------------------------------------------------------------------------
// GRACE GCN 2-layer forward, CSR-gather formulation, bf16 intermediates.
//   h1' = (X W1) * dinv      (bf16, pre-scaled by source dinv, MFMA bf16)
//   h2  = prelu(dinv_d*(h1'_d + sum_j h1'_es[j]) + b1)    (bf16)
//   g'  = (h2 W2) * dinv     (bf16, MFMA)
//   out = prelu(dinv_d*(g'_d + sum_j g'_es[j]) + b2)      (f32)
// CSR build via radix-partition (R6, unchanged). GEMM now uses
// v_mfma_f32_16x16x32_bf16 with zero LDS: W pre-transposed to WT[col][k] bf16
// in global (L2-hot), A/B fragments loaded as contiguous 16B per lane.
// R6's f32 vector GEMM was issue/occupancy-bound (VALUBusy 31%, occ 17%,
// 64KB LDS -> 2 blocks/CU, 100us for a 21us f32 roofline).
// ---------------------------------------------------------------------------

#define THREADS 256
#define SCAN_CHUNK 1024   // 256 threads x 4 elements
#define NBLK  128         // partition blocks (fixed chunking)
#define BINSH 7           // 128 nodes per bin
#define BINSZ 128
#define KMAX  1024        // max bins (supports n <= 131072)

typedef unsigned short bf16_t;
typedef __attribute__((ext_vector_type(8))) short bf16x8;
typedef __attribute__((ext_vector_type(4))) float f32x4;

__device__ __forceinline__ float bflo(unsigned int w) {
    union { unsigned int u; float f; } v; v.u = w << 16; return v.f;
}
__device__ __forceinline__ float bfhi(unsigned int w) {
    union { unsigned int u; float f; } v; v.u = w & 0xffff0000u; return v.f;
}
__device__ __forceinline__ unsigned int f2bf(float f) {  // RNE
    union { float f; unsigned int u; } v; v.f = f;
    return (v.u + 0x7fffu + ((v.u >> 16) & 1u)) >> 16;
}

// -------------------- pass 1: per-block bin histogram --------------------
__global__ __launch_bounds__(THREADS) void hist_kernel(const int* __restrict__ dst,
                                                       int* __restrict__ hist,
                                                       int e, int K, int chunk) {
    __shared__ int h[KMAX];
    int t = threadIdx.x, b = blockIdx.x;
    for (int i = t; i < K; i += THREADS) h[i] = 0;
    __syncthreads();
    int lo = b * chunk, hi = min(lo + chunk, e);
    for (int i = lo + t; i < hi; i += THREADS) atomicAdd(&h[dst[i] >> BINSH], 1);
    __syncthreads();
    for (int i = t; i < K; i += THREADS) hist[i * NBLK + b] = h[i];  // bin-major
}

// -------------------- exclusive scan over m elements (3 phases) ------------
__global__ void scan_phaseA_kernel(const int* __restrict__ in, int* __restrict__ bsum, int m) {
    __shared__ int sdata[256];
    int base = blockIdx.x * SCAN_CHUNK;
    int t = threadIdx.x;
    int s = 0;
#pragma unroll
    for (int k = 0; k < 4; ++k) {
        int idx = base + t * 4 + k;
        if (idx < m) s += in[idx];
    }
    sdata[t] = s;
    __syncthreads();
    for (int d = 128; d > 0; d >>= 1) {
        if (t < d) sdata[t] += sdata[t + d];
        __syncthreads();
    }
    if (t == 0) bsum[blockIdx.x] = sdata[0];
}

__global__ void scan_phaseB_kernel(int* __restrict__ bsum, int nb) {
    __shared__ int sdata[256];
    __shared__ int carry;
    int t = threadIdx.x;
    if (t == 0) carry = 0;
    __syncthreads();
    for (int base = 0; base < nb; base += 256) {
        int idx = base + t;
        int v = (idx < nb) ? bsum[idx] : 0;
        sdata[t] = v;
        __syncthreads();
        for (int d = 1; d < 256; d <<= 1) {
            int u = (t >= d) ? sdata[t - d] : 0;
            __syncthreads();
            sdata[t] += u;
            __syncthreads();
        }
        int excl = sdata[t] - v + carry;
        if (idx < nb) bsum[idx] = excl;
        int tot = sdata[255];
        __syncthreads();
        if (t == 0) carry += tot;
        __syncthreads();
    }
}

__global__ void scan_phaseC_kernel(const int* __restrict__ in, const int* __restrict__ bsum,
                                   int* __restrict__ outx, int m) {
    __shared__ int sdata[256];
    int base = blockIdx.x * SCAN_CHUNK;
    int t = threadIdx.x;
    int v[4];
    int s = 0;
#pragma unroll
    for (int k = 0; k < 4; ++k) {
        int idx = base + t * 4 + k;
        v[k] = (idx < m) ? in[idx] : 0;
        s += v[k];
    }
    sdata[t] = s;
    __syncthreads();
    for (int d = 1; d < 256; d <<= 1) {
        int u = (t >= d) ? sdata[t - d] : 0;
        __syncthreads();
        sdata[t] += u;
        __syncthreads();
    }
    int run = bsum[blockIdx.x] + sdata[t] - s;  // exclusive base
#pragma unroll
    for (int k = 0; k < 4; ++k) {
        int idx = base + t * 4 + k;
        if (idx < m) { outx[idx] = run; run += v[k]; }
    }
}

// -------------------- pass 2: rank via LDS + scatter to (bin,blk) segment ---
__global__ __launch_bounds__(THREADS) void rank_scatter_kernel(const int* __restrict__ src,
                                                               const int* __restrict__ dst,
                                                               const int* __restrict__ hoff,
                                                               unsigned int* __restrict__ sorted,
                                                               int e, int K, int chunk) {
    __shared__ int cntl[KMAX];
    __shared__ int basel[KMAX];
    int t = threadIdx.x, b = blockIdx.x;
    for (int i = t; i < K; i += THREADS) { cntl[i] = 0; basel[i] = hoff[i * NBLK + b]; }
    __syncthreads();
    int lo = b * chunk, hi = min(lo + chunk, e);
    for (int i = lo + t; i < hi; i += THREADS) {
        int d = dst[i];
        int bin = d >> BINSH;
        int r = atomicAdd(&cntl[bin], 1);
        sorted[basel[bin] + r] = (unsigned int)src[i] | ((unsigned int)(d & (BINSZ - 1)) << 25);
    }
}

// -------------------- pass 3: per-bin counting sort -> exact CSR ------------
__global__ __launch_bounds__(THREADS) void bin_build_kernel(const unsigned int* __restrict__ sorted,
                                                            const int* __restrict__ hoff,
                                                            float* __restrict__ dinv,
                                                            int* __restrict__ off,
                                                            int* __restrict__ cnt,
                                                            int* __restrict__ es,
                                                            int n, int e, int K) {
    __shared__ int scnt[BINSZ];
    __shared__ int soff[BINSZ];
    int b = blockIdx.x, t = threadIdx.x;
    int base = hoff[b * NBLK];
    int end  = (b + 1 < K) ? hoff[(b + 1) * NBLK] : e;
    int m = end - base;
    if (t < BINSZ) scnt[t] = 0;
    __syncthreads();
    for (int i = t; i < m; i += THREADS) atomicAdd(&scnt[sorted[base + i] >> 25], 1);
    __syncthreads();
    if (t < BINSZ) soff[t] = scnt[t];
    __syncthreads();
    for (int d = 1; d < BINSZ; d <<= 1) {
        int v = (t < BINSZ && t >= d) ? soff[t - d] : 0;
        __syncthreads();
        if (t < BINSZ) soff[t] += v;
        __syncthreads();
    }
    if (t < BINSZ) {
        int ex = soff[t] - scnt[t];     // exclusive
        int node = (b << BINSH) + t;
        if (node < n) {
            off[node]  = base + ex;
            cnt[node]  = scnt[t];
            dinv[node] = rsqrtf((float)(scnt[t] + 1));  // +1 self loop
        }
        soff[t] = ex;                   // local cursor
    }
    __syncthreads();
    for (int i = t; i < m; i += THREADS) {
        unsigned int pk = sorted[base + i];
        int pos = atomicAdd(&soff[pk >> 25], 1);
        es[base + pos] = (int)(pk & 0x01FFFFFFu);
    }
}

// -------------------- W transpose + bf16 convert: WT[c][k] = bf16(W[k][c]) --
__global__ void wt_kernel(const float* __restrict__ W, bf16_t* __restrict__ WT,
                          int Kdim, int C) {
    int tid = blockIdx.x * blockDim.x + threadIdx.x;
    if (tid >= Kdim * C) return;
    int c = tid / Kdim, k = tid % Kdim;          // WT write contiguous in k
    WT[(size_t)c * Kdim + k] = (bf16_t)f2bf(W[(size_t)k * C + c]);
}

// -------------------- MFMA GEMM: H = (X[n,128] @ W[128,OUTC]) * rowscale ----
// 4 waves/block, 16 rows/wave, zero LDS. A-frag: row=lane&15, k=(lane>>4)*8+j
// (contiguous 8 bf16). B-frag from WT[col][k]: col=lane&15, same k range.
// C/D: col=lane&15, row=(lane>>4)*4+reg (m89-verified layout).
template <int OUTC, bool XBF>
__global__ __launch_bounds__(THREADS) void gemm_mfma_kernel(const void* __restrict__ Xv,
                                                            const bf16_t* __restrict__ WT,
                                                            const float* __restrict__ rowscale,
                                                            bf16_t* __restrict__ H, int n) {
    constexpr int CT = OUTC / 16;            // col tiles
    int wid  = (int)threadIdx.x >> 6;
    int lane = (int)threadIdx.x & 63;
    int rbase = blockIdx.x * 64 + wid * 16;
    int col16 = lane & 15;
    int kgrp  = lane >> 4;                   // 0..3

    int rowA = rbase + col16;                // A rows indexed by lane&15
    if (rowA >= n) rowA = n - 1;             // clamp; stores guarded by D rows

    // ---- load A fragments for all 4 K-steps ----
    bf16x8 a[4];
#pragma unroll
    for (int ks = 0; ks < 4; ++ks) {
        int kb = ks * 32 + kgrp * 8;
        if constexpr (XBF) {
            a[ks] = *reinterpret_cast<const bf16x8*>((const bf16_t*)Xv + (size_t)rowA * 128 + kb);
        } else {
            const float* xp = (const float*)Xv + (size_t)rowA * 128 + kb;
            float4 x0 = *reinterpret_cast<const float4*>(xp);
            float4 x1 = *reinterpret_cast<const float4*>(xp + 4);
            bf16x8 t;
            t[0] = (short)f2bf(x0.x); t[1] = (short)f2bf(x0.y);
            t[2] = (short)f2bf(x0.z); t[3] = (short)f2bf(x0.w);
            t[4] = (short)f2bf(x1.x); t[5] = (short)f2bf(x1.y);
            t[6] = (short)f2bf(x1.z); t[7] = (short)f2bf(x1.w);
            a[ks] = t;
        }
    }

    // ---- rowscale for my 4 output rows ----
    int r0 = rbase + kgrp * 4;
    float sc[4];
#pragma unroll
    for (int j = 0; j < 4; ++j) sc[j] = (r0 + j < n) ? rowscale[r0 + j] : 0.f;

    // ---- K-accumulate per col tile ----
#pragma unroll
    for (int ct = 0; ct < CT; ++ct) {
        const bf16_t* wp = WT + (size_t)(ct * 16 + col16) * 128 + kgrp * 8;
        f32x4 acc = {0.f, 0.f, 0.f, 0.f};
#pragma unroll
        for (int ks = 0; ks < 4; ++ks) {
            bf16x8 b = *reinterpret_cast<const bf16x8*>(wp + ks * 32);
            acc = __builtin_amdgcn_mfma_f32_16x16x32_bf16(a[ks], b, acc, 0, 0, 0);
        }
#pragma unroll
        for (int j = 0; j < 4; ++j) {
            int r = r0 + j;
            if (r < n) H[(size_t)r * OUTC + ct * 16 + col16] = (bf16_t)f2bf(acc[j] * sc[j]);
        }
    }
}

// -------------------- CSR aggregate + bias + PReLU (fused, bf16 gather) -----
// out[i,:] = prelu( dinv[i]*(H'[i,:] + sum_j H'[es[j],:]) + b, a )
template <int F, bool OUTBF>
__global__ __launch_bounds__(THREADS) void agg_kernel(const bf16_t* __restrict__ H,
                                                      const float* __restrict__ dinv,
                                                      const int* __restrict__ off,
                                                      const int* __restrict__ cnt,
                                                      const int* __restrict__ es,
                                                      const float* __restrict__ bias,
                                                      const float* __restrict__ a_ptr,
                                                      void* __restrict__ outv, int n) {
    constexpr int TPN = F / 8;                 // threads per node (8 bf16 = 16B each)
    int node = blockIdx.x * (THREADS / TPN) + (int)threadIdx.x / TPN;
    int l8   = (int)threadIdx.x % TPN;
    if (node >= n) return;
    const int fbase = l8 * 8;

    float acc[8];
    {   // self term (H already pre-scaled by dinv[node])
        uint4 v = *reinterpret_cast<const uint4*>(H + (size_t)node * F + fbase);
        acc[0] = bflo(v.x); acc[1] = bfhi(v.x);
        acc[2] = bflo(v.y); acc[3] = bfhi(v.y);
        acc[4] = bflo(v.z); acc[5] = bfhi(v.z);
        acc[6] = bflo(v.w); acc[7] = bfhi(v.w);
    }

    int j0 = off[node];
    int m  = cnt[node];
    int i = 0;
    for (; i + 3 < m; i += 4) {
        int s0 = es[j0 + i], s1 = es[j0 + i + 1], s2 = es[j0 + i + 2], s3 = es[j0 + i + 3];
        uint4 v0 = *reinterpret_cast<const uint4*>(H + (size_t)s0 * F + fbase);
        uint4 v1 = *reinterpret_cast<const uint4*>(H + (size_t)s1 * F + fbase);
        uint4 v2 = *reinterpret_cast<const uint4*>(H + (size_t)s2 * F + fbase);
        uint4 v3 = *reinterpret_cast<const uint4*>(H + (size_t)s3 * F + fbase);
        acc[0] += (bflo(v0.x) + bflo(v1.x)) + (bflo(v2.x) + bflo(v3.x));
        acc[1] += (bfhi(v0.x) + bfhi(v1.x)) + (bfhi(v2.x) + bfhi(v3.x));
        acc[2] += (bflo(v0.y) + bflo(v1.y)) + (bflo(v2.y) + bflo(v3.y));
        acc[3] += (bfhi(v0.y) + bfhi(v1.y)) + (bfhi(v2.y) + bfhi(v3.y));
        acc[4] += (bflo(v0.z) + bflo(v1.z)) + (bflo(v2.z) + bflo(v3.z));
        acc[5] += (bfhi(v0.z) + bfhi(v1.z)) + (bfhi(v2.z) + bfhi(v3.z));
        acc[6] += (bflo(v0.w) + bflo(v1.w)) + (bflo(v2.w) + bflo(v3.w));
        acc[7] += (bfhi(v0.w) + bfhi(v1.w)) + (bfhi(v2.w) + bfhi(v3.w));
    }
    for (; i < m; ++i) {
        int s0 = es[j0 + i];
        uint4 v0 = *reinterpret_cast<const uint4*>(H + (size_t)s0 * F + fbase);
        acc[0] += bflo(v0.x); acc[1] += bfhi(v0.x);
        acc[2] += bflo(v0.y); acc[3] += bfhi(v0.y);
        acc[4] += bflo(v0.z); acc[5] += bfhi(v0.z);
        acc[6] += bflo(v0.w); acc[7] += bfhi(v0.w);
    }

    float di = dinv[node];
    float a  = *a_ptr;
    float4 b0 = *reinterpret_cast<const float4*>(bias + fbase);
    float4 b1 = *reinterpret_cast<const float4*>(bias + fbase + 4);
    float bb[8] = {b0.x, b0.y, b0.z, b0.w, b1.x, b1.y, b1.z, b1.w};
    float o[8];
#pragma unroll
    for (int k = 0; k < 8; ++k) {
        float v = acc[k] * di + bb[k];
        o[k] = v >= 0.f ? v : a * v;
    }

    if constexpr (OUTBF) {
        uint4 w;
        w.x = f2bf(o[0]) | (f2bf(o[1]) << 16);
        w.y = f2bf(o[2]) | (f2bf(o[3]) << 16);
        w.z = f2bf(o[4]) | (f2bf(o[5]) << 16);
        w.w = f2bf(o[6]) | (f2bf(o[7]) << 16);
        *reinterpret_cast<uint4*>((bf16_t*)outv + (size_t)node * F + fbase) = w;
    } else {
        float* op = (float*)outv + (size_t)node * F + fbase;
        *reinterpret_cast<float4*>(op)     = make_float4(o[0], o[1], o[2], o[3]);
        *reinterpret_cast<float4*>(op + 4) = make_float4(o[4], o[5], o[6], o[7]);
    }
}

extern "C" void kernel_launch(void* const* d_in, const int* in_sizes, int n_in,
                              void* d_out, int out_size, void* d_ws, size_t ws_size,
                              hipStream_t stream) {
    const float* x   = (const float*)d_in[0];
    const int*   ei  = (const int*)d_in[1];
    const float* W1  = (const float*)d_in[2];
    const float* b1  = (const float*)d_in[3];
    const float* W2  = (const float*)d_in[4];
    const float* b2  = (const float*)d_in[5];
    const float* a   = (const float*)d_in[6];

    const int IN  = 128;
    const int HID = 128;
    const int OUT = 64;
    const int n = in_sizes[0] / IN;       // 100000
    const int e = in_sizes[1] / 2;        // 1600000
    const int* src = ei;
    const int* dst = ei + e;

    const int K     = (n + BINSZ - 1) >> BINSH;   // 782 bins
    const int chunk = (e + NBLK - 1) / NBLK;      // 12500 edges/block
    const int M     = K * NBLK;                   // 100096 hist entries
    const int nb    = (M + SCAN_CHUNK - 1) / SCAN_CHUNK;

    auto align = [](size_t v) { return (v + 255) / 256 * 256; };
    char* ws = (char*)d_ws;
    size_t o = 0;
    int*          hist   = (int*)(ws + o);          o += align((size_t)M * 4);
    int*          hoff   = (int*)(ws + o);          o += align((size_t)M * 4);
    int*          bsum   = (int*)(ws + o);          o += align((size_t)nb * 4);
    unsigned int* sorted = (unsigned int*)(ws + o); o += align((size_t)e * 4);
    int*          es     = (int*)(ws + o);          o += align((size_t)e * 4);
    float*        dinv   = (float*)(ws + o);        o += align((size_t)n * 4);
    int*          off    = (int*)(ws + o);          o += align((size_t)n * 4);
    int*          cnt    = (int*)(ws + o);          o += align((size_t)n * 4);
    bf16_t*       h1     = (bf16_t*)(ws + o);       o += align((size_t)n * HID * 2);
    bf16_t*       h2     = (bf16_t*)(ws + o);       o += align((size_t)n * HID * 2);
    bf16_t*       g      = (bf16_t*)(ws + o);       o += align((size_t)n * OUT * 2);
    bf16_t*       WT1    = (bf16_t*)(ws + o);       o += align((size_t)IN * HID * 2);
    bf16_t*       WT2    = (bf16_t*)(ws + o);       o += align((size_t)HID * OUT * 2);

    float* out = (float*)d_out;

    // ---- W transposes (independent of CSR chain) ----
    wt_kernel<<<(IN * HID + THREADS - 1) / THREADS, THREADS, 0, stream>>>(W1, WT1, IN, HID);
    wt_kernel<<<(HID * OUT + THREADS - 1) / THREADS, THREADS, 0, stream>>>(W2, WT2, HID, OUT);

    // ---- CSR build: radix partition + per-bin counting sort ----
    hist_kernel<<<NBLK, THREADS, 0, stream>>>(dst, hist, e, K, chunk);
    scan_phaseA_kernel<<<nb, THREADS, 0, stream>>>(hist, bsum, M);
    scan_phaseB_kernel<<<1, THREADS, 0, stream>>>(bsum, nb);
    scan_phaseC_kernel<<<nb, THREADS, 0, stream>>>(hist, bsum, hoff, M);
    rank_scatter_kernel<<<NBLK, THREADS, 0, stream>>>(src, dst, hoff, sorted, e, K, chunk);
    bin_build_kernel<<<K, THREADS, 0, stream>>>(sorted, hoff, dinv, off, cnt, es, n, e, K);

    int gbG = (n + 63) / 64;

    // ---- layer 1 ----
    gemm_mfma_kernel<128, false><<<gbG, THREADS, 0, stream>>>(x, WT1, dinv, h1, n);
    {
        constexpr int NPB = THREADS / (128 / 8);   // 16 nodes/block
        int gb = (n + NPB - 1) / NPB;
        agg_kernel<128, true><<<gb, THREADS, 0, stream>>>(h1, dinv, off, cnt, es, b1, a, h2, n);
    }

    // ---- layer 2 ----
    gemm_mfma_kernel<64, true><<<gbG, THREADS, 0, stream>>>(h2, WT2, dinv, g, n);
    {
        constexpr int NPB = THREADS / (64 / 8);    // 32 nodes/block
        int gb = (n + NPB - 1) / NPB;
        agg_kernel<64, false><<<gb, THREADS, 0, stream>>>(g, dinv, off, cnt, es, b2, a, out, n);
    }

    (void)ws_size; (void)n_in; (void)out_size;
}

// Round 8
// 212.048 us; speedup vs baseline: 2.2006x; 1.0731x over previous
//
#include <hip/hip_runtime.h>

// ---------------------------------------------------------------------------
// GRACE GCN 2-layer forward, CSR-gather formulation, bf16 intermediates.
//   h1' = (X W1) * dinv      (bf16, pre-scaled by source dinv, MFMA bf16)
//   h2  = prelu(dinv_d*(h1'_d + sum_j h1'_es[j]) + b1)    (bf16)
//   g'  = (h2 W2) * dinv     (bf16, MFMA)
//   out = prelu(dinv_d*(g'_d + sum_j g'_es[j]) + b2)      (f32)
// R7->R8: agg edge loop deepened to 8 gathers in flight per lane (was 4) --
// agg<128> showed VALUBusy 27%, VGPR 28, 3.0 TB/s L2-miss: MLP/latency-bound.
// CSR partition NBLK 128->256 (was using only half the CUs).
// ---------------------------------------------------------------------------

#define THREADS 256
#define SCAN_CHUNK 1024   // 256 threads x 4 elements
#define NBLK  256         // partition blocks (fixed chunking)
#define BINSH 7           // 128 nodes per bin
#define BINSZ 128
#define KMAX  1024        // max bins (supports n <= 131072)

typedef unsigned short bf16_t;
typedef __attribute__((ext_vector_type(8))) short bf16x8;
typedef __attribute__((ext_vector_type(4))) float f32x4;

__device__ __forceinline__ float bflo(unsigned int w) {
    union { unsigned int u; float f; } v; v.u = w << 16; return v.f;
}
__device__ __forceinline__ float bfhi(unsigned int w) {
    union { unsigned int u; float f; } v; v.u = w & 0xffff0000u; return v.f;
}
__device__ __forceinline__ unsigned int f2bf(float f) {  // RNE
    union { float f; unsigned int u; } v; v.f = f;
    return (v.u + 0x7fffu + ((v.u >> 16) & 1u)) >> 16;
}

// -------------------- pass 1: per-block bin histogram --------------------
__global__ __launch_bounds__(THREADS) void hist_kernel(const int* __restrict__ dst,
                                                       int* __restrict__ hist,
                                                       int e, int K, int chunk) {
    __shared__ int h[KMAX];
    int t = threadIdx.x, b = blockIdx.x;
    for (int i = t; i < K; i += THREADS) h[i] = 0;
    __syncthreads();
    int lo = b * chunk, hi = min(lo + chunk, e);
    for (int i = lo + t; i < hi; i += THREADS) atomicAdd(&h[dst[i] >> BINSH], 1);
    __syncthreads();
    for (int i = t; i < K; i += THREADS) hist[i * NBLK + b] = h[i];  // bin-major
}

// -------------------- exclusive scan over m elements (3 phases) ------------
__global__ void scan_phaseA_kernel(const int* __restrict__ in, int* __restrict__ bsum, int m) {
    __shared__ int sdata[256];
    int base = blockIdx.x * SCAN_CHUNK;
    int t = threadIdx.x;
    int s = 0;
#pragma unroll
    for (int k = 0; k < 4; ++k) {
        int idx = base + t * 4 + k;
        if (idx < m) s += in[idx];
    }
    sdata[t] = s;
    __syncthreads();
    for (int d = 128; d > 0; d >>= 1) {
        if (t < d) sdata[t] += sdata[t + d];
        __syncthreads();
    }
    if (t == 0) bsum[blockIdx.x] = sdata[0];
}

__global__ void scan_phaseB_kernel(int* __restrict__ bsum, int nb) {
    __shared__ int sdata[256];
    __shared__ int carry;
    int t = threadIdx.x;
    if (t == 0) carry = 0;
    __syncthreads();
    for (int base = 0; base < nb; base += 256) {
        int idx = base + t;
        int v = (idx < nb) ? bsum[idx] : 0;
        sdata[t] = v;
        __syncthreads();
        for (int d = 1; d < 256; d <<= 1) {
            int u = (t >= d) ? sdata[t - d] : 0;
            __syncthreads();
            sdata[t] += u;
            __syncthreads();
        }
        int excl = sdata[t] - v + carry;
        if (idx < nb) bsum[idx] = excl;
        int tot = sdata[255];
        __syncthreads();
        if (t == 0) carry += tot;
        __syncthreads();
    }
}

__global__ void scan_phaseC_kernel(const int* __restrict__ in, const int* __restrict__ bsum,
                                   int* __restrict__ outx, int m) {
    __shared__ int sdata[256];
    int base = blockIdx.x * SCAN_CHUNK;
    int t = threadIdx.x;
    int v[4];
    int s = 0;
#pragma unroll
    for (int k = 0; k < 4; ++k) {
        int idx = base + t * 4 + k;
        v[k] = (idx < m) ? in[idx] : 0;
        s += v[k];
    }
    sdata[t] = s;
    __syncthreads();
    for (int d = 1; d < 256; d <<= 1) {
        int u = (t >= d) ? sdata[t - d] : 0;
        __syncthreads();
        sdata[t] += u;
        __syncthreads();
    }
    int run = bsum[blockIdx.x] + sdata[t] - s;  // exclusive base
#pragma unroll
    for (int k = 0; k < 4; ++k) {
        int idx = base + t * 4 + k;
        if (idx < m) { outx[idx] = run; run += v[k]; }
    }
}

// -------------------- pass 2: rank via LDS + scatter to (bin,blk) segment ---
__global__ __launch_bounds__(THREADS) void rank_scatter_kernel(const int* __restrict__ src,
                                                               const int* __restrict__ dst,
                                                               const int* __restrict__ hoff,
                                                               unsigned int* __restrict__ sorted,
                                                               int e, int K, int chunk) {
    __shared__ int cntl[KMAX];
    __shared__ int basel[KMAX];
    int t = threadIdx.x, b = blockIdx.x;
    for (int i = t; i < K; i += THREADS) { cntl[i] = 0; basel[i] = hoff[i * NBLK + b]; }
    __syncthreads();
    int lo = b * chunk, hi = min(lo + chunk, e);
    for (int i = lo + t; i < hi; i += THREADS) {
        int d = dst[i];
        int bin = d >> BINSH;
        int r = atomicAdd(&cntl[bin], 1);
        sorted[basel[bin] + r] = (unsigned int)src[i] | ((unsigned int)(d & (BINSZ - 1)) << 25);
    }
}

// -------------------- pass 3: per-bin counting sort -> exact CSR ------------
__global__ __launch_bounds__(THREADS) void bin_build_kernel(const unsigned int* __restrict__ sorted,
                                                            const int* __restrict__ hoff,
                                                            float* __restrict__ dinv,
                                                            int* __restrict__ off,
                                                            int* __restrict__ cnt,
                                                            int* __restrict__ es,
                                                            int n, int e, int K) {
    __shared__ int scnt[BINSZ];
    __shared__ int soff[BINSZ];
    int b = blockIdx.x, t = threadIdx.x;
    int base = hoff[b * NBLK];
    int end  = (b + 1 < K) ? hoff[(b + 1) * NBLK] : e;
    int m = end - base;
    if (t < BINSZ) scnt[t] = 0;
    __syncthreads();
    for (int i = t; i < m; i += THREADS) atomicAdd(&scnt[sorted[base + i] >> 25], 1);
    __syncthreads();
    if (t < BINSZ) soff[t] = scnt[t];
    __syncthreads();
    for (int d = 1; d < BINSZ; d <<= 1) {
        int v = (t < BINSZ && t >= d) ? soff[t - d] : 0;
        __syncthreads();
        if (t < BINSZ) soff[t] += v;
        __syncthreads();
    }
    if (t < BINSZ) {
        int ex = soff[t] - scnt[t];     // exclusive
        int node = (b << BINSH) + t;
        if (node < n) {
            off[node]  = base + ex;
            cnt[node]  = scnt[t];
            dinv[node] = rsqrtf((float)(scnt[t] + 1));  // +1 self loop
        }
        soff[t] = ex;                   // local cursor
    }
    __syncthreads();
    for (int i = t; i < m; i += THREADS) {
        unsigned int pk = sorted[base + i];
        int pos = atomicAdd(&soff[pk >> 25], 1);
        es[base + pos] = (int)(pk & 0x01FFFFFFu);
    }
}

// -------------------- W transpose + bf16 convert: WT[c][k] = bf16(W[k][c]) --
__global__ void wt_kernel(const float* __restrict__ W, bf16_t* __restrict__ WT,
                          int Kdim, int C) {
    int tid = blockIdx.x * blockDim.x + threadIdx.x;
    if (tid >= Kdim * C) return;
    int c = tid / Kdim, k = tid % Kdim;          // WT write contiguous in k
    WT[(size_t)c * Kdim + k] = (bf16_t)f2bf(W[(size_t)k * C + c]);
}

// -------------------- MFMA GEMM: H = (X[n,128] @ W[128,OUTC]) * rowscale ----
// 4 waves/block, 16 rows/wave, zero LDS. A-frag: row=lane&15, k=(lane>>4)*8+j
// (contiguous 8 bf16). B-frag from WT[col][k]: col=lane&15, same k range.
// C/D: col=lane&15, row=(lane>>4)*4+reg (m89-verified layout).
template <int OUTC, bool XBF>
__global__ __launch_bounds__(THREADS) void gemm_mfma_kernel(const void* __restrict__ Xv,
                                                            const bf16_t* __restrict__ WT,
                                                            const float* __restrict__ rowscale,
                                                            bf16_t* __restrict__ H, int n) {
    constexpr int CT = OUTC / 16;            // col tiles
    int wid  = (int)threadIdx.x >> 6;
    int lane = (int)threadIdx.x & 63;
    int rbase = blockIdx.x * 64 + wid * 16;
    int col16 = lane & 15;
    int kgrp  = lane >> 4;                   // 0..3

    int rowA = rbase + col16;                // A rows indexed by lane&15
    if (rowA >= n) rowA = n - 1;             // clamp; stores guarded by D rows

    // ---- load A fragments for all 4 K-steps ----
    bf16x8 a[4];
#pragma unroll
    for (int ks = 0; ks < 4; ++ks) {
        int kb = ks * 32 + kgrp * 8;
        if constexpr (XBF) {
            a[ks] = *reinterpret_cast<const bf16x8*>((const bf16_t*)Xv + (size_t)rowA * 128 + kb);
        } else {
            const float* xp = (const float*)Xv + (size_t)rowA * 128 + kb;
            float4 x0 = *reinterpret_cast<const float4*>(xp);
            float4 x1 = *reinterpret_cast<const float4*>(xp + 4);
            bf16x8 t;
            t[0] = (short)f2bf(x0.x); t[1] = (short)f2bf(x0.y);
            t[2] = (short)f2bf(x0.z); t[3] = (short)f2bf(x0.w);
            t[4] = (short)f2bf(x1.x); t[5] = (short)f2bf(x1.y);
            t[6] = (short)f2bf(x1.z); t[7] = (short)f2bf(x1.w);
            a[ks] = t;
        }
    }

    // ---- rowscale for my 4 output rows ----
    int r0 = rbase + kgrp * 4;
    float sc[4];
#pragma unroll
    for (int j = 0; j < 4; ++j) sc[j] = (r0 + j < n) ? rowscale[r0 + j] : 0.f;

    // ---- K-accumulate per col tile ----
#pragma unroll
    for (int ct = 0; ct < CT; ++ct) {
        const bf16_t* wp = WT + (size_t)(ct * 16 + col16) * 128 + kgrp * 8;
        f32x4 acc = {0.f, 0.f, 0.f, 0.f};
#pragma unroll
        for (int ks = 0; ks < 4; ++ks) {
            bf16x8 b = *reinterpret_cast<const bf16x8*>(wp + ks * 32);
            acc = __builtin_amdgcn_mfma_f32_16x16x32_bf16(a[ks], b, acc, 0, 0, 0);
        }
#pragma unroll
        for (int j = 0; j < 4; ++j) {
            int r = r0 + j;
            if (r < n) H[(size_t)r * OUTC + ct * 16 + col16] = (bf16_t)f2bf(acc[j] * sc[j]);
        }
    }
}

// -------------------- CSR aggregate + bias + PReLU (fused, bf16 gather) -----
// out[i,:] = prelu( dinv[i]*(H'[i,:] + sum_j H'[es[j],:]) + b, a )
// 8 gathers in flight per lane (MLP-bound at unroll 4: VALUBusy 27%, VGPR 28).
template <int F, bool OUTBF>
__global__ __launch_bounds__(THREADS) void agg_kernel(const bf16_t* __restrict__ H,
                                                      const float* __restrict__ dinv,
                                                      const int* __restrict__ off,
                                                      const int* __restrict__ cnt,
                                                      const int* __restrict__ es,
                                                      const float* __restrict__ bias,
                                                      const float* __restrict__ a_ptr,
                                                      void* __restrict__ outv, int n) {
    constexpr int TPN = F / 8;                 // threads per node (8 bf16 = 16B each)
    int node = blockIdx.x * (THREADS / TPN) + (int)threadIdx.x / TPN;
    int l8   = (int)threadIdx.x % TPN;
    if (node >= n) return;
    const int fbase = l8 * 8;

    float acc[8];
    {   // self term (H already pre-scaled by dinv[node])
        uint4 v = *reinterpret_cast<const uint4*>(H + (size_t)node * F + fbase);
        acc[0] = bflo(v.x); acc[1] = bfhi(v.x);
        acc[2] = bflo(v.y); acc[3] = bfhi(v.y);
        acc[4] = bflo(v.z); acc[5] = bfhi(v.z);
        acc[6] = bflo(v.w); acc[7] = bfhi(v.w);
    }

    int j0 = off[node];
    int m  = cnt[node];
    int i = 0;
    for (; i + 7 < m; i += 8) {
        int sidx[8];
#pragma unroll
        for (int u = 0; u < 8; ++u) sidx[u] = es[j0 + i + u];
        uint4 v[8];
#pragma unroll
        for (int u = 0; u < 8; ++u)
            v[u] = *reinterpret_cast<const uint4*>(H + (size_t)sidx[u] * F + fbase);
#pragma unroll
        for (int u = 0; u < 8; ++u) {
            acc[0] += bflo(v[u].x); acc[1] += bfhi(v[u].x);
            acc[2] += bflo(v[u].y); acc[3] += bfhi(v[u].y);
            acc[4] += bflo(v[u].z); acc[5] += bfhi(v[u].z);
            acc[6] += bflo(v[u].w); acc[7] += bfhi(v[u].w);
        }
    }
    for (; i + 1 < m; i += 2) {
        int s0 = es[j0 + i], s1 = es[j0 + i + 1];
        uint4 v0 = *reinterpret_cast<const uint4*>(H + (size_t)s0 * F + fbase);
        uint4 v1 = *reinterpret_cast<const uint4*>(H + (size_t)s1 * F + fbase);
        acc[0] += bflo(v0.x) + bflo(v1.x);
        acc[1] += bfhi(v0.x) + bfhi(v1.x);
        acc[2] += bflo(v0.y) + bflo(v1.y);
        acc[3] += bfhi(v0.y) + bfhi(v1.y);
        acc[4] += bflo(v0.z) + bflo(v1.z);
        acc[5] += bfhi(v0.z) + bfhi(v1.z);
        acc[6] += bflo(v0.w) + bflo(v1.w);
        acc[7] += bfhi(v0.w) + bfhi(v1.w);
    }
    if (i < m) {
        int s0 = es[j0 + i];
        uint4 v0 = *reinterpret_cast<const uint4*>(H + (size_t)s0 * F + fbase);
        acc[0] += bflo(v0.x); acc[1] += bfhi(v0.x);
        acc[2] += bflo(v0.y); acc[3] += bfhi(v0.y);
        acc[4] += bflo(v0.z); acc[5] += bfhi(v0.z);
        acc[6] += bflo(v0.w); acc[7] += bfhi(v0.w);
    }

    float di = dinv[node];
    float a  = *a_ptr;
    float4 b0 = *reinterpret_cast<const float4*>(bias + fbase);
    float4 b1 = *reinterpret_cast<const float4*>(bias + fbase + 4);
    float bb[8] = {b0.x, b0.y, b0.z, b0.w, b1.x, b1.y, b1.z, b1.w};
    float o[8];
#pragma unroll
    for (int k = 0; k < 8; ++k) {
        float v = acc[k] * di + bb[k];
        o[k] = v >= 0.f ? v : a * v;
    }

    if constexpr (OUTBF) {
        uint4 w;
        w.x = f2bf(o[0]) | (f2bf(o[1]) << 16);
        w.y = f2bf(o[2]) | (f2bf(o[3]) << 16);
        w.z = f2bf(o[4]) | (f2bf(o[5]) << 16);
        w.w = f2bf(o[6]) | (f2bf(o[7]) << 16);
        *reinterpret_cast<uint4*>((bf16_t*)outv + (size_t)node * F + fbase) = w;
    } else {
        float* op = (float*)outv + (size_t)node * F + fbase;
        *reinterpret_cast<float4*>(op)     = make_float4(o[0], o[1], o[2], o[3]);
        *reinterpret_cast<float4*>(op + 4) = make_float4(o[4], o[5], o[6], o[7]);
    }
}

extern "C" void kernel_launch(void* const* d_in, const int* in_sizes, int n_in,
                              void* d_out, int out_size, void* d_ws, size_t ws_size,
                              hipStream_t stream) {
    const float* x   = (const float*)d_in[0];
    const int*   ei  = (const int*)d_in[1];
    const float* W1  = (const float*)d_in[2];
    const float* b1  = (const float*)d_in[3];
    const float* W2  = (const float*)d_in[4];
    const float* b2  = (const float*)d_in[5];
    const float* a   = (const float*)d_in[6];

    const int IN  = 128;
    const int HID = 128;
    const int OUT = 64;
    const int n = in_sizes[0] / IN;       // 100000
    const int e = in_sizes[1] / 2;        // 1600000
    const int* src = ei;
    const int* dst = ei + e;

    const int K     = (n + BINSZ - 1) >> BINSH;   // 782 bins
    const int chunk = (e + NBLK - 1) / NBLK;      // 6250 edges/block
    const int M     = K * NBLK;                   // ~200k hist entries
    const int nb    = (M + SCAN_CHUNK - 1) / SCAN_CHUNK;

    auto align = [](size_t v) { return (v + 255) / 256 * 256; };
    char* ws = (char*)d_ws;
    size_t o = 0;
    int*          hist   = (int*)(ws + o);          o += align((size_t)M * 4);
    int*          hoff   = (int*)(ws + o);          o += align((size_t)M * 4);
    int*          bsum   = (int*)(ws + o);          o += align((size_t)nb * 4);
    unsigned int* sorted = (unsigned int*)(ws + o); o += align((size_t)e * 4);
    int*          es     = (int*)(ws + o);          o += align((size_t)e * 4);
    float*        dinv   = (float*)(ws + o);        o += align((size_t)n * 4);
    int*          off    = (int*)(ws + o);          o += align((size_t)n * 4);
    int*          cnt    = (int*)(ws + o);          o += align((size_t)n * 4);
    bf16_t*       h1     = (bf16_t*)(ws + o);       o += align((size_t)n * HID * 2);
    bf16_t*       h2     = (bf16_t*)(ws + o);       o += align((size_t)n * HID * 2);
    bf16_t*       g      = (bf16_t*)(ws + o);       o += align((size_t)n * OUT * 2);
    bf16_t*       WT1    = (bf16_t*)(ws + o);       o += align((size_t)IN * HID * 2);
    bf16_t*       WT2    = (bf16_t*)(ws + o);       o += align((size_t)HID * OUT * 2);

    float* out = (float*)d_out;

    // ---- W transposes (independent of CSR chain) ----
    wt_kernel<<<(IN * HID + THREADS - 1) / THREADS, THREADS, 0, stream>>>(W1, WT1, IN, HID);
    wt_kernel<<<(HID * OUT + THREADS - 1) / THREADS, THREADS, 0, stream>>>(W2, WT2, HID, OUT);

    // ---- CSR build: radix partition + per-bin counting sort ----
    hist_kernel<<<NBLK, THREADS, 0, stream>>>(dst, hist, e, K, chunk);
    scan_phaseA_kernel<<<nb, THREADS, 0, stream>>>(hist, bsum, M);
    scan_phaseB_kernel<<<1, THREADS, 0, stream>>>(bsum, nb);
    scan_phaseC_kernel<<<nb, THREADS, 0, stream>>>(hist, bsum, hoff, M);
    rank_scatter_kernel<<<NBLK, THREADS, 0, stream>>>(src, dst, hoff, sorted, e, K, chunk);
    bin_build_kernel<<<K, THREADS, 0, stream>>>(sorted, hoff, dinv, off, cnt, es, n, e, K);

    int gbG = (n + 63) / 64;

    // ---- layer 1 ----
    gemm_mfma_kernel<128, false><<<gbG, THREADS, 0, stream>>>(x, WT1, dinv, h1, n);
    {
        constexpr int NPB = THREADS / (128 / 8);   // 16 nodes/block
        int gb = (n + NPB - 1) / NPB;
        agg_kernel<128, true><<<gb, THREADS, 0, stream>>>(h1, dinv, off, cnt, es, b1, a, h2, n);
    }

    // ---- layer 2 ----
    gemm_mfma_kernel<64, true><<<gbG, THREADS, 0, stream>>>(h2, WT2, dinv, g, n);
    {
        constexpr int NPB = THREADS / (64 / 8);    // 32 nodes/block
        int gb = (n + NPB - 1) / NPB;
        agg_kernel<64, false><<<gb, THREADS, 0, stream>>>(g, dinv, off, cnt, es, b2, a, out, n);
    }

    (void)ws_size; (void)n_in; (void)out_size;
}